// Round 6
// baseline (6068.344 us; speedup 1.0000x reference)
//
#include <hip/hip_runtime.h>
#include <hip/hip_bf16.h>
#include <hip/hip_cooperative_groups.h>

namespace cg = cooperative_groups;

// ---------------------------------------------------------------------------
// 2-layer LSTM decoder, B=64, T=25, H=2048, IN=OUT=66, hardtanh feedback.
// v6: single persistent cooperative kernel (512 blocks x 512 threads,
// 2 blocks/CU) doing prep + 25 steps with grid.sync() between phases:
//   A: gp0 = h0@Whh0, gp1 = h1@Whh1 (512 tiles) + FC(h1)->x (blocks 0..65)
//   B: c0 = x@Wih0 + gp0 + cell0 -> h0      (blocks 0..255)
//   C: c1 = h0@Wih1 + gp1 + cell1 -> h1     (blocks 0..255)
// Cast pass is read-coalesced (scatter moved to writes). v5 kernel path kept
// as fallback if cooperative launch is rejected.
// ---------------------------------------------------------------------------

typedef short bfrag  __attribute__((ext_vector_type(8)));   // 8 bf16 (4 VGPR)
typedef float accv   __attribute__((ext_vector_type(4)));   // 4 fp32 acc
typedef float vfloat4 __attribute__((ext_vector_type(4)));
typedef unsigned short usvec8 __attribute__((ext_vector_type(8)));

#define LD8(p) (*(const bfrag*)(p))

__device__ __forceinline__ unsigned short f2bf(float x) {
    unsigned int u = __float_as_uint(x);
    unsigned int r = u + 0x7FFFu + ((u >> 16) & 1u);   // RTNE
    return (unsigned short)(r >> 16);
}
__device__ __forceinline__ float bf2f(unsigned short u) {
    return __uint_as_float(((unsigned int)u) << 16);
}

// Activation fragment layout ("Ap", KC chunks of 32 k-elements):
//   (b, k) -> [((b>>4)*KC + (k>>5))*512 + (((k>>3)&3)*16 + (b&15))*8 + (k&7)]
__device__ __forceinline__ int ap_idx(int b, int j, int KC) {
    return (((b >> 4) * KC + (j >> 5)) << 9) + ((((j >> 3) & 3) * 16 + (b & 15)) << 3) + (j & 7);
}

// ------------------------- prep sub-tasks (shared) --------------------------
// Big cast, read-coalesced: item i = (matrix, row, k-octet).
__device__ __forceinline__ void prep_big(int i,
        const float* __restrict__ s0, const float* __restrict__ s1, const float* __restrict__ s2,
        unsigned short* __restrict__ d0, unsigned short* __restrict__ d1, unsigned short* __restrict__ d2) {
    int a = i >> 21, r = i & 2097151;
    const float* src = (a == 0) ? s0 : (a == 1) ? s1 : s2;
    unsigned short* dst = (a == 0) ? d0 : (a == 1) ? d1 : d2;
    int row = r >> 8, kq = r & 255;
    const float* sp = src + (size_t)row * 2048 + kq * 8;
    vfloat4 v0 = *(const vfloat4*)sp;
    vfloat4 v1 = *(const vfloat4*)(sp + 4);
    int g = row >> 11, u = row & 2047;
    int jb = u >> 3, un = u & 7, p = g >> 1, hi = g & 1;
    int n = hi * 8 + un, kc = kq >> 2, quad = kq & 3, ln = quad * 16 + n;
    usvec8 uv = { f2bf(v0.x), f2bf(v0.y), f2bf(v0.z), f2bf(v0.w),
                  f2bf(v1.x), f2bf(v1.y), f2bf(v1.z), f2bf(v1.w) };
    *(usvec8*)(dst + (((size_t)(jb * 2 + p) * 64 + kc) << 9) + ln * 8) = uv;
}
__device__ __forceinline__ void prep_wih0(int i, const float* __restrict__ wih0,
                                          unsigned short* __restrict__ wih0p) {
    int row = i / 12, kq = i % 12;           // KC=3 -> 12 octets/row (k padded to 96)
    int g = row >> 11, u = row & 2047;
    int jb = u >> 3, un = u & 7, p = g >> 1, hi = g & 1;
    int n = hi * 8 + un, kc = kq >> 2, quad = kq & 3, ln = quad * 16 + n;
    unsigned short e[8];
    #pragma unroll
    for (int j = 0; j < 8; ++j) {
        int k = kq * 8 + j;
        e[j] = (k < 66) ? f2bf(wih0[row * 66 + k]) : (unsigned short)0;
    }
    usvec8 uv = { e[0], e[1], e[2], e[3], e[4], e[5], e[6], e[7] };
    *(usvec8*)(wih0p + (((size_t)(jb * 2 + p) * 3 + kc) << 9) + ln * 8) = uv;
}
__device__ __forceinline__ void prep_state(int i, const float* __restrict__ hiddens,
        const float* __restrict__ cells, unsigned short* __restrict__ h0,
        unsigned short* __restrict__ h1, float* __restrict__ c0, float* __restrict__ c1) {
    int b = i >> 11, j = i & 2047;
    h0[ap_idx(b, j, 64)] = f2bf(hiddens[i]);
    h1[ap_idx(b, j, 64)] = f2bf(hiddens[131072 + i]);
    int ci = (j >> 3) * 512 + b * 8 + (j & 7);
    c0[ci] = cells[i];
    c1[ci] = cells[131072 + i];
}
__device__ __forceinline__ void prep_xb(int i, const float* __restrict__ inputs,
                                        unsigned short* __restrict__ xbuf) {
    int jo = i & 7, ln = (i >> 3) & 63;
    int t2 = i >> 9, kc = t2 % 3, m = t2 / 3;
    int b = m * 16 + (ln & 15);
    int k = kc * 32 + (ln >> 4) * 8 + jo;
    xbuf[i] = (k < 66) ? f2bf(inputs[b * 66 + k]) : (unsigned short)0;
}

// ------------------------- GEMM helpers (v5-proven) -------------------------
__device__ __forceinline__ void gemm8(const unsigned short* __restrict__ Ap,
                                      const unsigned short* __restrict__ Bp,
                                      int jb, int lane, int w, accv (&acc)[4][2]) {
    constexpr int PF = 2, NC = 8;
    const unsigned short* a = Ap + ((size_t)w << 9) + lane * 8;
    const unsigned short* b = Bp + (((size_t)(2 * jb) * 64 + w) << 9) + lane * 8;
    bfrag fA[PF][4], fB[PF][2];
    auto issue = [&](int i) {
        int s = i % PF;
        const unsigned short* ap = a + ((size_t)i << 12);
        const unsigned short* bp = b + ((size_t)i << 12);
        fA[s][0] = LD8(ap);
        fA[s][1] = LD8(ap + (64 << 9));
        fA[s][2] = LD8(ap + 2 * (64 << 9));
        fA[s][3] = LD8(ap + 3 * (64 << 9));
        fB[s][0] = LD8(bp);
        fB[s][1] = LD8(bp + (64 << 9));
    };
    #pragma unroll
    for (int i = 0; i < PF; ++i) issue(i);
    #pragma unroll
    for (int i = 0; i < NC; ++i) {
        int s = i % PF;
        #pragma unroll
        for (int mi = 0; mi < 4; ++mi)
            #pragma unroll
            for (int p = 0; p < 2; ++p)
                acc[mi][p] = __builtin_amdgcn_mfma_f32_16x16x32_bf16(fA[s][mi], fB[s][p], acc[mi][p], 0, 0, 0);
        if (i + PF < NC) issue(i + PF);
    }
}

__device__ __forceinline__ void store_gsm(float (*gsm)[64][32], accv (&acc)[4][2],
                                          int lane, int w) {
    int n = lane & 15, quad = lane >> 4;
    #pragma unroll
    for (int mi = 0; mi < 4; ++mi)
        #pragma unroll
        for (int p = 0; p < 2; ++p)
            #pragma unroll
            for (int r = 0; r < 4; ++r) {
                int R = mi * 16 + quad * 4 + r;          // batch
                int C = p * 16 + n;                      // gate*8 + unit
                gsm[w][R][C ^ ((R & 3) << 3)] = acc[mi][p][r];
            }
}

__device__ __forceinline__ void gp_epilogue(float (*gsm)[64][32], float* __restrict__ gp,
                                            int jb, int tid) {
    for (int idx = tid; idx < 2048; idx += 512) {
        int b = idx >> 5, C = idx & 31;
        int Cs = C ^ ((b & 3) << 3);
        float s = 0.f;
        #pragma unroll
        for (int w8 = 0; w8 < 8; ++w8) s += gsm[w8][b][Cs];
        gp[(size_t)jb * 2048 + idx] = s;
    }
}

__device__ __forceinline__ void cell_epilogue(float (*gsm)[64][32],
        const float* __restrict__ gp, const float* __restrict__ bsum,
        float* __restrict__ c_state, unsigned short* __restrict__ h_out,
        int jb, int tid) {
    int b = tid >> 3, jj = tid & 7;
    const float* gpt = gp + (size_t)jb * 2048 + b * 32 + jj;
    float g4[4];
    #pragma unroll
    for (int g = 0; g < 4; ++g) {
        int Cp = (g * 8 + jj) ^ ((b & 3) << 3);
        float s = gpt[g * 8];
        #pragma unroll
        for (int w8 = 0; w8 < 8; ++w8) s += gsm[w8][b][Cp];
        g4[g] = s;
    }
    int j = jb * 8 + jj;
    float iv = 1.f / (1.f + __expf(-(g4[0] + bsum[j])));
    float fv = 1.f / (1.f + __expf(-(g4[1] + bsum[2048 + j])));
    float gv = tanhf(g4[2] + bsum[4096 + j]);
    float ov = 1.f / (1.f + __expf(-(g4[3] + bsum[6144 + j])));
    float cn = fv * c_state[jb * 512 + tid] + iv * gv;
    float hn = ov * tanhf(cn);
    c_state[jb * 512 + tid] = cn;
    h_out[ap_idx(b, j, 64)] = f2bf(hn);
}

__device__ __forceinline__ void c0_body(float (*gsm)[64][32],
        const unsigned short* __restrict__ xbuf, const unsigned short* __restrict__ wih0p,
        const float* __restrict__ gp0, const float* __restrict__ bsum0,
        float* __restrict__ c0, unsigned short* __restrict__ h0,
        int jb, int tid, int lane, int w) {
    accv acc[4][2] = {};
    if (w < 3) {
        const unsigned short* bp = wih0p + (((size_t)(2 * jb) * 3 + w) << 9) + lane * 8;
        bfrag xw0 = LD8(bp), xw1 = LD8(bp + (3 << 9));
        #pragma unroll
        for (int mi = 0; mi < 4; ++mi) {
            bfrag xa = LD8(xbuf + (((size_t)mi * 3 + w) << 9) + lane * 8);
            acc[mi][0] = __builtin_amdgcn_mfma_f32_16x16x32_bf16(xa, xw0, acc[mi][0], 0, 0, 0);
            acc[mi][1] = __builtin_amdgcn_mfma_f32_16x16x32_bf16(xa, xw1, acc[mi][1], 0, 0, 0);
        }
    }
    store_gsm(gsm, acc, lane, w);
    __syncthreads();
    cell_epilogue(gsm, gp0, bsum0, c0, h0, jb, tid);
}

// FC for one output unit o: out[.,tprev,o] and x feedback. Uses `red` (LDS).
__device__ __forceinline__ void fc_eval(const unsigned short* __restrict__ h1,
        const float* __restrict__ fcw, const float* __restrict__ fcb,
        float* __restrict__ outg, unsigned short* __restrict__ xbuf,
        int tprev, int o, int tid, int lane, int w, float* red) {
    int b = lane;
    const float* wrow = fcw + (size_t)o * 2048;
    float acc = 0.f;
    for (int kc = w; kc < 64; kc += 8) {
        const unsigned short* hp = h1 + (((size_t)(b >> 4) * 64 + kc) << 9) + (b & 15) * 8;
        const float* wp = wrow + kc * 32;
        #pragma unroll
        for (int q = 0; q < 4; ++q) {
            usvec8 hv = *(const usvec8*)(hp + q * 128);
            vfloat4 w0 = *(const vfloat4*)(wp + q * 8);
            vfloat4 w1 = *(const vfloat4*)(wp + q * 8 + 4);
            acc = fmaf(bf2f(hv[0]), w0.x, acc);
            acc = fmaf(bf2f(hv[1]), w0.y, acc);
            acc = fmaf(bf2f(hv[2]), w0.z, acc);
            acc = fmaf(bf2f(hv[3]), w0.w, acc);
            acc = fmaf(bf2f(hv[4]), w1.x, acc);
            acc = fmaf(bf2f(hv[5]), w1.y, acc);
            acc = fmaf(bf2f(hv[6]), w1.z, acc);
            acc = fmaf(bf2f(hv[7]), w1.w, acc);
        }
    }
    red[w * 64 + b] = acc;
    __syncthreads();
    if (tid < 64) {
        float v = fcb[o];
        #pragma unroll
        for (int q = 0; q < 8; ++q) v += red[q * 64 + tid];
        v = fminf(1.f, fmaxf(-1.f, v));
        outg[((size_t)tid * 25 + tprev) * 66 + o] = v;
        xbuf[ap_idx(tid, o, 3)] = f2bf(v);
    }
}

// --------------------------- persistent mega kernel -------------------------
__global__ __launch_bounds__(512, 4) void mega(
        const float* inputs, const float* hiddens, const float* cells,
        const float* W_ih0, const float* W_hh0, const float* b_ih0, const float* b_hh0,
        const float* W_ih1, const float* W_hh1, const float* b_ih1, const float* b_hh1,
        const float* fc_w, const float* fc_b, float* outg,
        unsigned short* whh0p, unsigned short* wih1p, unsigned short* whh1p,
        unsigned short* wih0p, unsigned short* h0, unsigned short* h1,
        unsigned short* xbuf, float* c0, float* c1,
        float* bsum0, float* bsum1, float* gp0, float* gp1) {
    cg::grid_group grid = cg::this_grid();
    __shared__ float gsm[8][64][32];                      // 64 KB
    const int tid = threadIdx.x, lane = tid & 63, w = tid >> 6;
    const int bid = blockIdx.x;
    const int gtid = bid * 512 + tid;
    constexpr int GSZ = 512 * 512;

    // ---- prep (grid-stride)
    for (int i = gtid; i < 6291456; i += GSZ)
        prep_big(i, W_hh0, W_ih1, W_hh1, whh0p, wih1p, whh1p);
    for (int i = gtid; i < 98304; i += GSZ) prep_wih0(i, W_ih0, wih0p);
    for (int i = gtid; i < 131072; i += GSZ) prep_state(i, hiddens, cells, h0, h1, c0, c1);
    for (int i = gtid; i < 6144; i += GSZ) prep_xb(i, inputs, xbuf);
    for (int i = gtid; i < 8192; i += GSZ) {
        bsum0[i] = b_ih0[i] + b_hh0[i];
        bsum1[i] = b_ih1[i] + b_hh1[i];
    }
    grid.sync();

    for (int t = 0; t < 25; ++t) {
        // ---- Phase A: recurrent partials + FC feedback
        {
            int l = bid >> 8, jb = bid & 255;
            accv acc[4][2] = {};
            gemm8(l ? h1 : h0, l ? whh1p : whh0p, jb, lane, w, acc);
            store_gsm(gsm, acc, lane, w);
            __syncthreads();
            gp_epilogue(gsm, l ? gp1 : gp0, jb, tid);
            if (bid < 66 && t > 0) {
                __syncthreads();
                fc_eval(h1, fc_w, fc_b, outg, xbuf, t - 1, bid, tid, lane, w, &gsm[0][0][0]);
            }
        }
        grid.sync();
        // ---- Phase B: x-GEMM + cell0 -> h0
        if (bid < 256)
            c0_body(gsm, xbuf, wih0p, gp0, bsum0, c0, h0, bid, tid, lane, w);
        grid.sync();
        // ---- Phase C: h0-GEMM + cell1 -> h1
        if (bid < 256) {
            accv acc[4][2] = {};
            gemm8(h0, wih1p, bid, lane, w, acc);
            store_gsm(gsm, acc, lane, w);
            __syncthreads();
            cell_epilogue(gsm, gp1, bsum1, c1, h1, bid, tid);
        }
        grid.sync();
    }
    // ---- final FC: out[24]
    if (bid < 66)
        fc_eval(h1, fc_w, fc_b, outg, xbuf, 24, bid, tid, lane, w, &gsm[0][0][0]);
}

// --------------------------- fallback kernels (v5 path) ---------------------
__global__ __launch_bounds__(256) void prepk(
        const float* __restrict__ W_hh0, const float* __restrict__ W_ih1, const float* __restrict__ W_hh1,
        unsigned short* __restrict__ whh0p, unsigned short* __restrict__ wih1p, unsigned short* __restrict__ whh1p,
        const float* __restrict__ inputs, const float* __restrict__ hiddens,
        const float* __restrict__ cells,  const float* __restrict__ W_ih0,
        unsigned short* __restrict__ wih0p,
        unsigned short* __restrict__ h0, unsigned short* __restrict__ h1,
        float* __restrict__ c0, float* __restrict__ c1,
        unsigned short* __restrict__ xbuf,
        float* __restrict__ bsum0, float* __restrict__ bsum1,
        const float* __restrict__ b_ih0, const float* __restrict__ b_hh0,
        const float* __restrict__ b_ih1, const float* __restrict__ b_hh1) {
    int bid = blockIdx.x;
    if (bid < 24576) { prep_big(bid * 256 + threadIdx.x, W_hh0, W_ih1, W_hh1, whh0p, wih1p, whh1p); return; }
    int i = (bid - 24576) * 256 + threadIdx.x;
    if (i < 98304) { prep_wih0(i, W_ih0, wih0p); return; }
    i -= 98304;
    if (i < 131072) { prep_state(i, hiddens, cells, h0, h1, c0, c1); return; }
    i -= 131072;
    if (i < 6144) { prep_xb(i, inputs, xbuf); return; }
    i -= 6144;
    if (i < 8192) { bsum0[i] = b_ih0[i] + b_hh0[i]; bsum1[i] = b_ih1[i] + b_hh1[i]; }
}

__global__ __launch_bounds__(512, 4) void pstep(
        const unsigned short* __restrict__ h0, const unsigned short* __restrict__ h1,
        const unsigned short* __restrict__ Bp0, const unsigned short* __restrict__ Bp1,
        const float* __restrict__ fcw, const float* __restrict__ fcb,
        float* __restrict__ gp0, float* __restrict__ gp1,
        unsigned short* __restrict__ xbuf, float* __restrict__ outg, int t) {
    __shared__ float gsm[8][64][32];
    int tid = threadIdx.x, lane = tid & 63, w = tid >> 6;
    int bid = blockIdx.x;
    if (bid < 66) {
        if (t == 0) return;
        fc_eval(h1, fcw, fcb, outg, xbuf, t - 1, bid, tid, lane, w, &gsm[0][0][0]);
        return;
    }
    int l = (bid - 66) >> 8, jb = (bid - 66) & 255;
    accv acc[4][2] = {};
    gemm8(l ? h1 : h0, l ? Bp1 : Bp0, jb, lane, w, acc);
    store_gsm(gsm, acc, lane, w);
    __syncthreads();
    gp_epilogue(gsm, l ? gp1 : gp0, jb, tid);
}

__global__ __launch_bounds__(512, 4) void c0step(
        const unsigned short* __restrict__ xbuf, const unsigned short* __restrict__ wih0p,
        const float* __restrict__ gp0, const float* __restrict__ bsum0,
        float* __restrict__ c0, unsigned short* __restrict__ h0) {
    __shared__ float gsm[8][64][32];
    int tid = threadIdx.x;
    c0_body(gsm, xbuf, wih0p, gp0, bsum0, c0, h0, blockIdx.x, tid, tid & 63, tid >> 6);
}

__global__ __launch_bounds__(512, 4) void c1step(
        const unsigned short* __restrict__ h0, const unsigned short* __restrict__ wih1p,
        const float* __restrict__ gp1, const float* __restrict__ bsum1,
        float* __restrict__ c1, unsigned short* __restrict__ h1) {
    __shared__ float gsm[8][64][32];
    int tid = threadIdx.x, lane = tid & 63, w = tid >> 6;
    accv acc[4][2] = {};
    gemm8(h0, wih1p, blockIdx.x, lane, w, acc);
    store_gsm(gsm, acc, lane, w);
    __syncthreads();
    cell_epilogue(gsm, gp1, bsum1, c1, h1, blockIdx.x, tid);
}

// ---------------------------------------------------------------------------
extern "C" void kernel_launch(void* const* d_in, const int* in_sizes, int n_in,
                              void* d_out, int out_size, void* d_ws, size_t ws_size,
                              hipStream_t stream) {
    (void)in_sizes; (void)n_in; (void)out_size; (void)ws_size;
    const float* inputs  = (const float*)d_in[0];
    const float* hiddens = (const float*)d_in[1];
    const float* cells   = (const float*)d_in[2];
    const float* W_ih0   = (const float*)d_in[3];
    const float* W_hh0   = (const float*)d_in[4];
    const float* b_ih0   = (const float*)d_in[5];
    const float* b_hh0   = (const float*)d_in[6];
    const float* W_ih1   = (const float*)d_in[7];
    const float* W_hh1   = (const float*)d_in[8];
    const float* b_ih1   = (const float*)d_in[9];
    const float* b_hh1   = (const float*)d_in[10];
    const float* fc_w    = (const float*)d_in[11];
    const float* fc_b    = (const float*)d_in[12];
    float* out = (float*)d_out;

    // workspace layout (~108 MB)
    unsigned short* whh0p = (unsigned short*)d_ws;     // 16777216 shorts each
    unsigned short* wih1p = whh0p + 16777216;
    unsigned short* whh1p = wih1p + 16777216;
    unsigned short* wih0p = whh1p + 16777216;          // 786432 (Bp KC=3)
    unsigned short* h0    = wih0p + 786432;            // 131072 (Ap KC=64), in-place
    unsigned short* h1    = h0 + 131072;
    unsigned short* xb    = h1 + 131072;               // 6144 (Ap KC=3)
    float* c0    = (float*)(xb + 6144);                // 131072 fp32 each
    float* c1    = c0 + 131072;
    float* bsum0 = c1 + 131072;                        // 8192 fp32 each
    float* bsum1 = bsum0 + 8192;
    float* gp0   = bsum1 + 8192;                       // 524288 fp32 each (2 MB)
    float* gp1   = gp0 + 524288;

    void* params[] = {
        (void*)&inputs, (void*)&hiddens, (void*)&cells,
        (void*)&W_ih0, (void*)&W_hh0, (void*)&b_ih0, (void*)&b_hh0,
        (void*)&W_ih1, (void*)&W_hh1, (void*)&b_ih1, (void*)&b_hh1,
        (void*)&fc_w, (void*)&fc_b, (void*)&out,
        (void*)&whh0p, (void*)&wih1p, (void*)&whh1p, (void*)&wih0p,
        (void*)&h0, (void*)&h1, (void*)&xb, (void*)&c0, (void*)&c1,
        (void*)&bsum0, (void*)&bsum1, (void*)&gp0, (void*)&gp1
    };
    hipError_t err = hipLaunchCooperativeKernel((const void*)mega, dim3(512), dim3(512),
                                                params, 0, stream);
    if (err != hipSuccess) {
        // fallback: v5-style multi-launch path
        prepk<<<25528, 256, 0, stream>>>(W_hh0, W_ih1, W_hh1, whh0p, wih1p, whh1p,
                                         inputs, hiddens, cells, W_ih0,
                                         wih0p, h0, h1, c0, c1, xb,
                                         bsum0, bsum1, b_ih0, b_hh0, b_ih1, b_hh1);
        for (int t = 0; t < 25; ++t) {
            pstep<<<578, 512, 0, stream>>>(h0, h1, whh0p, whh1p, fc_w, fc_b,
                                           gp0, gp1, xb, out, t);
            c0step<<<256, 512, 0, stream>>>(xb, wih0p, gp0, bsum0, c0, h0);
            c1step<<<256, 512, 0, stream>>>(h0, wih1p, gp1, bsum1, c1, h1);
        }
        pstep<<<66, 512, 0, stream>>>(h0, h1, whh0p, whh1p, fc_w, fc_b,
                                      gp0, gp1, xb, out, 25);
    }
}